// Round 5
// baseline (271.127 us; speedup 1.0000x reference)
//
#include <hip/hip_runtime.h>
#include <hip/hip_fp16.h>

// Problem constants (fixed by the reference setup)
constexpr int N = 4096;
constexpr int D = 512;
constexpr int NT = 32;                   // 4096 / 128 tile-rows
constexpr int NBLK = NT * (NT + 1) / 2;  // 528 upper-triangle tiles
constexpr int BCAP = 256;                // per-block candidate cap (expect ~51)
constexpr float CAND_TH = 0.62f;         // loss threshold: |t| > 0.12 (~2.7 sigma)

typedef _Float16 f16x8 __attribute__((ext_vector_type(8)));
typedef float f32x4 __attribute__((ext_vector_type(4)));

// raw barrier / fine-grained vmcnt (AITER-style pipeline; compiler must not
// see these as __syncthreads or it inserts a full vmcnt(0) drain)
#define BAR() asm volatile("s_barrier" ::: "memory")
#define WAITV8() asm volatile("s_waitcnt vmcnt(8)" ::: "memory")
#define WAITV0() asm volatile("s_waitcnt vmcnt(0)" ::: "memory")

// async 16B/lane global->LDS (wave-uniform LDS base + lane*16)
__device__ __forceinline__ void load_lds16(const _Float16* g, _Float16* l) {
  __builtin_amdgcn_global_load_lds(
      (const __attribute__((address_space(1))) void*)g,
      (__attribute__((address_space(3))) void*)l, 16, 0, 0);
}

// ws layout:
//   ws+0       f32 blk_sumv[528]; f32 blk_sump[528];
//              u32 blk_cntv[528]; u32 blk_cntp[528]; u32 blk_zero[528]; u32 blk_ccnt[528]
//   ws+12672   f32 cand[528*BCAP]
//   ws+553344  f16 Xh[N*D]
constexpr int CAND_OFF = 12672;
constexpr int XH_OFF = 553344;

// ---------------- K0: fp32 -> f16 convert ----------------
__global__ void prep_kernel(const float4* __restrict__ X4,
                            ushort4* __restrict__ Xh4) {
  int gid = blockIdx.x * 256 + threadIdx.x;  // grid exactly N*D/4 threads
  float4 v = X4[gid];
  ushort4 o;
  o.x = __half_as_ushort(__float2half_rn(v.x));
  o.y = __half_as_ushort(__float2half_rn(v.y));
  o.z = __half_as_ushort(__float2half_rn(v.z));
  o.w = __half_as_ushort(__float2half_rn(v.w));
  Xh4[gid] = o;
}

// ---------------- K1: upper-triangle tiled X*X^T + fused loss epilogue ----------------
// Double-buffered LDS (2 x 128x64 halves per operand), raw-barrier pipeline:
//   issue(it+1) -> s_waitcnt vmcnt(8) -> s_barrier -> compute(it)
// so the drain only covers loads issued one full iteration ago.
// XOR swizzle: LDS pos p of row r holds global chunk p^(r&7).
__global__ __launch_bounds__(256, 2) void gemm_stats_kernel(
    const _Float16* __restrict__ Xh, const int* __restrict__ tgt,
    float* __restrict__ slots, float* __restrict__ cand) {
  float* blk_sumv = slots;
  float* blk_sump = slots + NBLK;
  unsigned* blk_cntv = (unsigned*)(slots + 2 * NBLK);
  unsigned* blk_cntp = (unsigned*)(slots + 3 * NBLK);
  unsigned* blk_zero = (unsigned*)(slots + 4 * NBLK);
  unsigned* blk_ccnt = (unsigned*)(slots + 5 * NBLK);

  __shared__ _Float16 As[2 * 128 * 64];  // 32 KB (double-buffered)
  __shared__ _Float16 Bs[2 * 128 * 64];  // 32 KB
  __shared__ int tA[128], tB[128];
  __shared__ float redf[2][4];
  __shared__ unsigned redu[3][4];
  __shared__ float bc_buf[BCAP];
  __shared__ unsigned bc_cnt;

  int tid = threadIdx.x;
  if (tid == 0) bc_cnt = 0;

  // decode upper-triangle tile (br <= bc)
  int id = blockIdx.x, br = 0;
  while (id >= (NT - br)) { id -= (NT - br); br++; }
  int bc = br + id;

  if (tid < 128) tA[tid] = tgt[br * 128 + tid];
  else           tB[tid - 128] = tgt[bc * 128 + (tid - 128)];

  int lane = tid & 63, wave = tid >> 6;
  int wm = (wave >> 1) << 6;
  int wn = (wave & 1) << 6;
  int lrow = lane & 15;
  int q4 = lane >> 4;  // quad 0..3
  int x7 = lrow & 7;   // swizzle key for ds_read side
  int quad4 = q4 * 4;

  // staging: issue i (0..3) covers chunks C=(i*4+wave)*64+lane;
  // row=C>>3, lds pos p=C&7 holds global chunk p^(row&7)
  int srow[4], scol[4], sdst[4];
#pragma unroll
  for (int i = 0; i < 4; i++) {
    int C = (i * 4 + wave) * 64 + lane;
    int row = C >> 3, p = C & 7;
    srow[i] = row;
    scol[i] = (p ^ (row & 7)) * 8;
    sdst[i] = (i * 4 + wave) * 512;
  }
  const _Float16* Arow = Xh + (size_t)(br * 128) * D;
  const _Float16* Brow = Xh + (size_t)(bc * 128) * D;

  auto issue = [&](int k0, int sel) {
#pragma unroll
    for (int i = 0; i < 4; i++) {
      load_lds16(Arow + srow[i] * D + k0 + scol[i], As + sel * 8192 + sdst[i]);
      load_lds16(Brow + srow[i] * D + k0 + scol[i], Bs + sel * 8192 + sdst[i]);
    }
  };

  f32x4 acc[4][4] = {};

  __syncthreads();  // tA/tB, bc_cnt visible; drains all prior vm/lgkm
  issue(0, 0);      // cold prefetch of tile 0

#pragma unroll
  for (int it = 0; it < 8; ++it) {
    int sel = it & 1;
    if (it > 0) BAR();              // all waves done READING buffer sel^1
    if (it < 7) {
      issue((it + 1) * 64, sel ^ 1);  // prefetch next into the other buffer
      WAITV8();                        // drain only tile-it's 8 loads (~free)
    } else {
      WAITV0();
    }
    BAR();                          // all waves' tile-it deposits visible
#pragma unroll
    for (int ks = 0; ks < 64; ks += 32) {
      int c0 = ks >> 3;
      f16x8 af[4], bf[4];
#pragma unroll
      for (int mi = 0; mi < 4; mi++)
        af[mi] = *(const f16x8*)&As[sel * 8192 + (wm + mi * 16 + lrow) * 64 +
                                    ((c0 + q4) ^ x7) * 8];
#pragma unroll
      for (int ni = 0; ni < 4; ni++)
        bf[ni] = *(const f16x8*)&Bs[sel * 8192 + (wn + ni * 16 + lrow) * 64 +
                                    ((c0 + q4) ^ x7) * 8];
#pragma unroll
      for (int mi = 0; mi < 4; mi++)
#pragma unroll
        for (int ni = 0; ni < 4; ni++)
          acc[mi][ni] = __builtin_amdgcn_mfma_f32_16x16x32_f16(
              af[mi], bf[ni], acc[mi][ni], 0, 0, 0);
    }
  }

  // ---- fused epilogue: masks, hinge, stats, candidate filter (LDS only) ----
  int ti[4][4], tj[4];
#pragma unroll
  for (int ni = 0; ni < 4; ni++) tj[ni] = tB[wn + ni * 16 + lrow];
#pragma unroll
  for (int mi = 0; mi < 4; mi++)
#pragma unroll
    for (int r = 0; r < 4; r++) ti[mi][r] = tA[wm + mi * 16 + quad4 + r];

  float lsv = 0.f, lsp = 0.f;
  unsigned lcv = 0, lcp = 0, lz = 0;
  int ibase = br * 128 + wm + quad4;
  int jbase = bc * 128 + wn + lrow;

#pragma unroll
  for (int mi = 0; mi < 4; mi++)
#pragma unroll
    for (int ni = 0; ni < 4; ni++)
#pragma unroll
      for (int r = 0; r < 4; r++) {
        float s = acc[mi][ni][r];
        int i = ibase + mi * 16 + r;
        int j = jbase + ni * 16;
        bool valid = j > i;  // strict upper triangle; results doubled at the end
        bool pos = valid && (ti[mi][r] == tj[ni]);
        float t = pos ? -s : s;
        float loss = fmaxf(0.5f + t, 0.0f);
        if (valid) { lsv += s; lcv++; if (loss == 0.0f) lz++; }
        if (pos) { lsp += s; lcp++; }
        // explicit wave-aggregated compaction: 1 LDS atomic per wave per site
        bool cp = valid && (loss > CAND_TH);
        unsigned long long m = __ballot(cp);
        if (m) {
          unsigned wb = 0;
          if (lane == 0) wb = atomicAdd(&bc_cnt, (unsigned)__popcll(m));
          wb = (unsigned)__shfl((int)wb, 0);
          if (cp) {
            unsigned pos2 = wb + (unsigned)__popcll(m & ((1ull << lane) - 1));
            if (pos2 < BCAP) bc_buf[pos2] = loss;
          }
        }
      }

  // block reduction -> plain stores to per-block slots (NO global atomics)
#pragma unroll
  for (int o = 32; o > 0; o >>= 1) {
    lsv += __shfl_down(lsv, o);
    lsp += __shfl_down(lsp, o);
    lcv += __shfl_down(lcv, o);
    lcp += __shfl_down(lcp, o);
    lz  += __shfl_down(lz, o);
  }
  if (lane == 0) {
    redf[0][wave] = lsv; redf[1][wave] = lsp;
    redu[0][wave] = lcv; redu[1][wave] = lcp; redu[2][wave] = lz;
  }
  __syncthreads();
  unsigned n = bc_cnt < BCAP ? bc_cnt : BCAP;
  if (tid == 0) {
    int b = blockIdx.x;
    blk_sumv[b] = redf[0][0] + redf[0][1] + redf[0][2] + redf[0][3];
    blk_sump[b] = redf[1][0] + redf[1][1] + redf[1][2] + redf[1][3];
    blk_cntv[b] = redu[0][0] + redu[0][1] + redu[0][2] + redu[0][3];
    blk_cntp[b] = redu[1][0] + redu[1][1] + redu[1][2] + redu[1][3];
    blk_zero[b] = redu[2][0] + redu[2][1] + redu[2][2] + redu[2][3];
    blk_ccnt[b] = n;
  }
  for (unsigned i2 = tid; i2 < n; i2 += 256)
    cand[blockIdx.x * BCAP + i2] = bc_buf[i2];
}

// branchless sorted-desc top-10 insert
__device__ __forceinline__ void ins10(float (&t)[10], float v) {
#pragma unroll
  for (int k = 9; k > 0; k--) t[k] = fmaxf(t[k], fminf(v, t[k - 1]));
  t[0] = fmaxf(t[0], v);
}

// ---------------- K2: stats + coalesced per-block top-10 + outputs ----------------
__global__ void finalize_kernel(const float* __restrict__ slots,
                                const float* __restrict__ cand,
                                float* __restrict__ out) {
  const float* blk_sumv = slots;
  const float* blk_sump = slots + NBLK;
  const unsigned* blk_cntv = (const unsigned*)(slots + 2 * NBLK);
  const unsigned* blk_cntp = (const unsigned*)(slots + 3 * NBLK);
  const unsigned* blk_zero = (const unsigned*)(slots + 4 * NBLK);
  const unsigned* blk_ccnt = (const unsigned*)(slots + 5 * NBLK);

  __shared__ unsigned cnts[NBLK];
  __shared__ float Lf[256 * 10];
  __shared__ float rf[2][4];
  __shared__ unsigned ru[3][4];

  int tid = threadIdx.x;
  int lane = tid & 63, wave = tid >> 6;

  // phase 1: stats + preload counts
  float sv = 0.f, sp = 0.f;
  unsigned cv = 0, cp = 0, zz = 0;
  for (int b = tid; b < NBLK; b += 256) {
    sv += blk_sumv[b]; sp += blk_sump[b];
    cv += blk_cntv[b]; cp += blk_cntp[b]; zz += blk_zero[b];
    cnts[b] = blk_ccnt[b];
  }
#pragma unroll
  for (int o = 32; o > 0; o >>= 1) {
    sv += __shfl_down(sv, o);
    sp += __shfl_down(sp, o);
    cv += __shfl_down(cv, o);
    cp += __shfl_down(cp, o);
    zz += __shfl_down(zz, o);
  }
  if (lane == 0) {
    rf[0][wave] = sv; rf[1][wave] = sp;
    ru[0][wave] = cv; ru[1][wave] = cp; ru[2][wave] = zz;
  }
  __syncthreads();

  // phase 2: top-10; each block's region read coalesced by the whole block
  float t[10];
#pragma unroll
  for (int k = 0; k < 10; k++) t[k] = -1e30f;
  for (int b = 0; b < NBLK; b++) {
    unsigned n = cnts[b];
    for (unsigned i = tid; i < n; i += 256) ins10(t, cand[b * BCAP + i]);
  }
#pragma unroll
  for (int k = 0; k < 10; k++) Lf[tid * 10 + k] = t[k];

  // pairwise tree merge of 256 sorted lists
  for (int s = 128; s >= 1; s >>= 1) {
    __syncthreads();
    if (tid < s) {
#pragma unroll
      for (int k = 0; k < 10; k++) ins10(t, Lf[(tid + s) * 10 + k]);
#pragma unroll
      for (int k = 0; k < 10; k++) Lf[tid * 10 + k] = t[k];
    }
  }
  __syncthreads();

  if (tid == 0) {
    float topsum = 0.f;
#pragma unroll
    for (int k = 0; k < 10; k++) topsum += t[k];
    float tsv = rf[0][0] + rf[0][1] + rf[0][2] + rf[0][3];
    float tsp = rf[1][0] + rf[1][1] + rf[1][2] + rf[1][3];
    unsigned tcv = ru[0][0] + ru[0][1] + ru[0][2] + ru[0][3];
    unsigned tcp = ru[1][0] + ru[1][1] + ru[1][2] + ru[1][3];
    unsigned tzz = ru[2][0] + ru[2][1] + ru[2][2] + ru[2][3];
    // full-matrix multiset = upper-triangle doubled: top-20 mean == top-10 mean,
    // counts double in numerator and denominator (cancel in means)
    out[0] = topsum * 0.1f;
    out[1] = (float)(2u * tzz);
    out[2] = tsp / (float)tcp;
    out[3] = (tsv - tsp) / (float)(tcv - tcp);
  }
}

extern "C" void kernel_launch(void* const* d_in, const int* in_sizes, int n_in,
                              void* d_out, int out_size, void* d_ws, size_t ws_size,
                              hipStream_t stream) {
  const float* X = (const float*)d_in[0];
  const int* tgt = (const int*)d_in[1];
  float* out = (float*)d_out;
  char* ws = (char*)d_ws;

  float* slots = (float*)ws;
  float* cand = (float*)(ws + CAND_OFF);
  _Float16* Xh = (_Float16*)(ws + XH_OFF);

  prep_kernel<<<(N * D / 4) / 256, 256, 0, stream>>>((const float4*)X,
                                                     (ushort4*)Xh);
  gemm_stats_kernel<<<NBLK, 256, 0, stream>>>(Xh, tgt, slots, cand);
  finalize_kernel<<<1, 256, 0, stream>>>(slots, cand, out);
}

// Round 6
// 175.986 us; speedup vs baseline: 1.5406x; 1.5406x over previous
//
#include <hip/hip_runtime.h>
#include <hip/hip_fp16.h>

// Problem constants (fixed by the reference setup)
constexpr int N = 4096;
constexpr int D = 512;
constexpr int NT = 32;                   // 4096 / 128 tile-rows
constexpr int NBLK = NT * (NT + 1) / 2;  // 528 upper-triangle tiles
constexpr int BCAP = 128;                // per-block candidate cap (expect ~51, 10-sigma safe)
constexpr float CAND_TH = 0.62f;         // loss threshold: |t| > 0.12 (~2.7 sigma)
constexpr float SENT = -1e30f;           // sentinel for unused candidate slots

typedef _Float16 f16x8 __attribute__((ext_vector_type(8)));
typedef float f32x4 __attribute__((ext_vector_type(4)));

// raw barrier / fine-grained vmcnt (AITER-style pipeline; compiler must not
// see these as __syncthreads or it inserts a full vmcnt(0) drain)
#define BAR() asm volatile("s_barrier" ::: "memory")
#define WAITV8() asm volatile("s_waitcnt vmcnt(8)" ::: "memory")
#define WAITV0() asm volatile("s_waitcnt vmcnt(0)" ::: "memory")

// async 16B/lane global->LDS (wave-uniform LDS base + lane*16)
__device__ __forceinline__ void load_lds16(const _Float16* g, _Float16* l) {
  __builtin_amdgcn_global_load_lds(
      (const __attribute__((address_space(1))) void*)g,
      (__attribute__((address_space(3))) void*)l, 16, 0, 0);
}

// ws layout:
//   ws+0       f32 blk_sumv[528]; f32 blk_sump[528];
//              u32 blk_cntv[528]; u32 blk_cntp[528]; u32 blk_zero[528]
//   ws+10560   f32 cand[528*BCAP]          (sentinel-padded, fixed stride)
//   ws+280896  (align 64) -> 280960 f16 Xh[N*D]
constexpr int CAND_OFF = 10560;
constexpr int XH_OFF = 280960;

// ---------------- K0: fp32 -> f16 convert ----------------
__global__ void prep_kernel(const float4* __restrict__ X4,
                            ushort4* __restrict__ Xh4) {
  int gid = blockIdx.x * 256 + threadIdx.x;  // grid exactly N*D/4 threads
  float4 v = X4[gid];
  ushort4 o;
  o.x = __half_as_ushort(__float2half_rn(v.x));
  o.y = __half_as_ushort(__float2half_rn(v.y));
  o.z = __half_as_ushort(__float2half_rn(v.z));
  o.w = __half_as_ushort(__float2half_rn(v.w));
  Xh4[gid] = o;
}

// ---------------- K1: upper-triangle tiled X*X^T + fused loss epilogue ----------------
// Double-buffered LDS (2 x 128x64 halves per operand), raw-barrier pipeline:
//   issue(it+1) -> s_waitcnt vmcnt(8) -> s_barrier -> compute(it)
// XOR swizzle: LDS pos p of row r holds global chunk p^(r&7).
__global__ __launch_bounds__(256, 2) void gemm_stats_kernel(
    const _Float16* __restrict__ Xh, const int* __restrict__ tgt,
    float* __restrict__ slots, float* __restrict__ cand) {
  float* blk_sumv = slots;
  float* blk_sump = slots + NBLK;
  unsigned* blk_cntv = (unsigned*)(slots + 2 * NBLK);
  unsigned* blk_cntp = (unsigned*)(slots + 3 * NBLK);
  unsigned* blk_zero = (unsigned*)(slots + 4 * NBLK);

  __shared__ _Float16 As[2 * 128 * 64];  // 32 KB (double-buffered)
  __shared__ _Float16 Bs[2 * 128 * 64];  // 32 KB
  __shared__ int tA[128], tB[128];
  __shared__ float redf[2][4];
  __shared__ unsigned redu[3][4];
  __shared__ float bc_buf[BCAP];
  __shared__ unsigned bc_cnt;

  int tid = threadIdx.x;
  if (tid == 0) bc_cnt = 0;

  // decode upper-triangle tile (br <= bc)
  int id = blockIdx.x, br = 0;
  while (id >= (NT - br)) { id -= (NT - br); br++; }
  int bc = br + id;

  if (tid < 128) tA[tid] = tgt[br * 128 + tid];
  else           tB[tid - 128] = tgt[bc * 128 + (tid - 128)];

  int lane = tid & 63, wave = tid >> 6;
  int wm = (wave >> 1) << 6;
  int wn = (wave & 1) << 6;
  int lrow = lane & 15;
  int q4 = lane >> 4;  // quad 0..3
  int x7 = lrow & 7;   // swizzle key for ds_read side
  int quad4 = q4 * 4;

  // staging: issue i (0..3) covers chunks C=(i*4+wave)*64+lane;
  // row=C>>3, lds pos p=C&7 holds global chunk p^(row&7)
  int srow[4], scol[4], sdst[4];
#pragma unroll
  for (int i = 0; i < 4; i++) {
    int C = (i * 4 + wave) * 64 + lane;
    int row = C >> 3, p = C & 7;
    srow[i] = row;
    scol[i] = (p ^ (row & 7)) * 8;
    sdst[i] = (i * 4 + wave) * 512;
  }
  const _Float16* Arow = Xh + (size_t)(br * 128) * D;
  const _Float16* Brow = Xh + (size_t)(bc * 128) * D;

  auto issue = [&](int k0, int sel) {
#pragma unroll
    for (int i = 0; i < 4; i++) {
      load_lds16(Arow + srow[i] * D + k0 + scol[i], As + sel * 8192 + sdst[i]);
      load_lds16(Brow + srow[i] * D + k0 + scol[i], Bs + sel * 8192 + sdst[i]);
    }
  };

  f32x4 acc[4][4] = {};

  __syncthreads();  // tA/tB, bc_cnt visible; drains all prior vm/lgkm
  issue(0, 0);      // cold prefetch of tile 0

#pragma unroll
  for (int it = 0; it < 8; ++it) {
    int sel = it & 1;
    if (it > 0) BAR();                // all waves done READING buffer sel^1
    if (it < 7) {
      issue((it + 1) * 64, sel ^ 1);  // prefetch next into the other buffer
      WAITV8();                       // drain only tile-it's 8 loads (~free)
    } else {
      WAITV0();
    }
    BAR();                            // all waves' tile-it deposits visible
#pragma unroll
    for (int ks = 0; ks < 64; ks += 32) {
      int c0 = ks >> 3;
      f16x8 af[4], bf[4];
#pragma unroll
      for (int mi = 0; mi < 4; mi++)
        af[mi] = *(const f16x8*)&As[sel * 8192 + (wm + mi * 16 + lrow) * 64 +
                                    ((c0 + q4) ^ x7) * 8];
#pragma unroll
      for (int ni = 0; ni < 4; ni++)
        bf[ni] = *(const f16x8*)&Bs[sel * 8192 + (wn + ni * 16 + lrow) * 64 +
                                    ((c0 + q4) ^ x7) * 8];
#pragma unroll
      for (int mi = 0; mi < 4; mi++)
#pragma unroll
        for (int ni = 0; ni < 4; ni++)
          acc[mi][ni] = __builtin_amdgcn_mfma_f32_16x16x32_f16(
              af[mi], bf[ni], acc[mi][ni], 0, 0, 0);
    }
  }

  // ---- fused epilogue: masks, hinge, stats, candidate filter (LDS only) ----
  int ti[4][4], tj[4];
#pragma unroll
  for (int ni = 0; ni < 4; ni++) tj[ni] = tB[wn + ni * 16 + lrow];
#pragma unroll
  for (int mi = 0; mi < 4; mi++)
#pragma unroll
    for (int r = 0; r < 4; r++) ti[mi][r] = tA[wm + mi * 16 + quad4 + r];

  float lsv = 0.f, lsp = 0.f;
  unsigned lcv = 0, lcp = 0, lz = 0;
  int ibase = br * 128 + wm + quad4;
  int jbase = bc * 128 + wn + lrow;

#pragma unroll
  for (int mi = 0; mi < 4; mi++)
#pragma unroll
    for (int ni = 0; ni < 4; ni++)
#pragma unroll
      for (int r = 0; r < 4; r++) {
        float s = acc[mi][ni][r];
        int i = ibase + mi * 16 + r;
        int j = jbase + ni * 16;
        bool valid = j > i;  // strict upper triangle; results doubled at the end
        bool pos = valid && (ti[mi][r] == tj[ni]);
        float t = pos ? -s : s;
        float loss = fmaxf(0.5f + t, 0.0f);
        if (valid) { lsv += s; lcv++; if (loss == 0.0f) lz++; }
        if (pos) { lsp += s; lcp++; }
        // explicit wave-aggregated compaction: 1 LDS atomic per wave per site
        bool cp = valid && (loss > CAND_TH);
        unsigned long long m = __ballot(cp);
        if (m) {
          unsigned wb = 0;
          if (lane == 0) wb = atomicAdd(&bc_cnt, (unsigned)__popcll(m));
          wb = (unsigned)__shfl((int)wb, 0);
          if (cp) {
            unsigned pos2 = wb + (unsigned)__popcll(m & ((1ull << lane) - 1));
            if (pos2 < BCAP) bc_buf[pos2] = loss;
          }
        }
      }

  // block reduction -> plain stores to per-block slots (NO global atomics)
#pragma unroll
  for (int o = 32; o > 0; o >>= 1) {
    lsv += __shfl_down(lsv, o);
    lsp += __shfl_down(lsp, o);
    lcv += __shfl_down(lcv, o);
    lcp += __shfl_down(lcp, o);
    lz  += __shfl_down(lz, o);
  }
  if (lane == 0) {
    redf[0][wave] = lsv; redf[1][wave] = lsp;
    redu[0][wave] = lcv; redu[1][wave] = lcp; redu[2][wave] = lz;
  }
  __syncthreads();
  unsigned n = bc_cnt < BCAP ? bc_cnt : BCAP;
  if (tid == 0) {
    int b = blockIdx.x;
    blk_sumv[b] = redf[0][0] + redf[0][1] + redf[0][2] + redf[0][3];
    blk_sump[b] = redf[1][0] + redf[1][1] + redf[1][2] + redf[1][3];
    blk_cntv[b] = redu[0][0] + redu[0][1] + redu[0][2] + redu[0][3];
    blk_cntp[b] = redu[1][0] + redu[1][1] + redu[1][2] + redu[1][3];
    blk_zero[b] = redu[2][0] + redu[2][1] + redu[2][2] + redu[2][3];
  }
  // sentinel-padded fixed-size region: finalize streams it with no bounds data
  for (unsigned i2 = tid; i2 < BCAP; i2 += 256)
    cand[blockIdx.x * BCAP + i2] = (i2 < n) ? bc_buf[i2] : SENT;
}

// branchless sorted-desc top-10 insert
__device__ __forceinline__ void ins10(float (&t)[10], float v) {
#pragma unroll
  for (int k = 9; k > 0; k--) t[k] = fmaxf(t[k], fminf(v, t[k - 1]));
  t[0] = fmaxf(t[0], v);
}

// ---------------- K2: stats + flat streaming top-10 + outputs ----------------
__global__ void finalize_kernel(const float* __restrict__ slots,
                                const float* __restrict__ cand,
                                float* __restrict__ out) {
  const float* blk_sumv = slots;
  const float* blk_sump = slots + NBLK;
  const unsigned* blk_cntv = (const unsigned*)(slots + 2 * NBLK);
  const unsigned* blk_cntp = (const unsigned*)(slots + 3 * NBLK);
  const unsigned* blk_zero = (const unsigned*)(slots + 4 * NBLK);

  __shared__ float Lf[256 * 10];
  __shared__ float rf[2][4];
  __shared__ unsigned ru[3][4];

  int tid = threadIdx.x;
  int lane = tid & 63, wave = tid >> 6;

  // phase 1: stats
  float sv = 0.f, sp = 0.f;
  unsigned cv = 0, cp = 0, zz = 0;
  for (int b = tid; b < NBLK; b += 256) {
    sv += blk_sumv[b]; sp += blk_sump[b];
    cv += blk_cntv[b]; cp += blk_cntp[b]; zz += blk_zero[b];
  }
#pragma unroll
  for (int o = 32; o > 0; o >>= 1) {
    sv += __shfl_down(sv, o);
    sp += __shfl_down(sp, o);
    cv += __shfl_down(cv, o);
    cp += __shfl_down(cp, o);
    zz += __shfl_down(zz, o);
  }
  if (lane == 0) {
    rf[0][wave] = sv; rf[1][wave] = sp;
    ru[0][wave] = cv; ru[1][wave] = cp; ru[2][wave] = zz;
  }

  // phase 2: flat coalesced streaming top-10 (fixed trip count, sentinel-padded)
  float t[10];
#pragma unroll
  for (int k = 0; k < 10; k++) t[k] = SENT;
  for (int g = tid; g < NBLK * BCAP; g += 256) ins10(t, cand[g]);
#pragma unroll
  for (int k = 0; k < 10; k++) Lf[tid * 10 + k] = t[k];

  // pairwise tree merge of 256 sorted lists
  for (int s = 128; s >= 1; s >>= 1) {
    __syncthreads();
    if (tid < s) {
#pragma unroll
      for (int k = 0; k < 10; k++) ins10(t, Lf[(tid + s) * 10 + k]);
#pragma unroll
      for (int k = 0; k < 10; k++) Lf[tid * 10 + k] = t[k];
    }
  }
  __syncthreads();

  if (tid == 0) {
    float topsum = 0.f;
#pragma unroll
    for (int k = 0; k < 10; k++) topsum += t[k];
    float tsv = rf[0][0] + rf[0][1] + rf[0][2] + rf[0][3];
    float tsp = rf[1][0] + rf[1][1] + rf[1][2] + rf[1][3];
    unsigned tcv = ru[0][0] + ru[0][1] + ru[0][2] + ru[0][3];
    unsigned tcp = ru[1][0] + ru[1][1] + ru[1][2] + ru[1][3];
    unsigned tzz = ru[2][0] + ru[2][1] + ru[2][2] + ru[2][3];
    // full-matrix multiset = upper-triangle doubled: top-20 mean == top-10 mean,
    // counts double in numerator and denominator (cancel in means)
    out[0] = topsum * 0.1f;
    out[1] = (float)(2u * tzz);
    out[2] = tsp / (float)tcp;
    out[3] = (tsv - tsp) / (float)(tcv - tcp);
  }
}

extern "C" void kernel_launch(void* const* d_in, const int* in_sizes, int n_in,
                              void* d_out, int out_size, void* d_ws, size_t ws_size,
                              hipStream_t stream) {
  const float* X = (const float*)d_in[0];
  const int* tgt = (const int*)d_in[1];
  float* out = (float*)d_out;
  char* ws = (char*)d_ws;

  float* slots = (float*)ws;
  float* cand = (float*)(ws + CAND_OFF);
  _Float16* Xh = (_Float16*)(ws + XH_OFF);

  prep_kernel<<<(N * D / 4) / 256, 256, 0, stream>>>((const float4*)X,
                                                     (ushort4*)Xh);
  gemm_stats_kernel<<<NBLK, 256, 0, stream>>>(Xh, tgt, slots, cand);
  finalize_kernel<<<1, 256, 0, stream>>>(slots, cand, out);
}

// Round 7
// 109.456 us; speedup vs baseline: 2.4770x; 1.6078x over previous
//
#include <hip/hip_runtime.h>
#include <hip/hip_fp16.h>

// Problem constants (fixed by the reference setup)
constexpr int N = 4096;
constexpr int D = 512;
constexpr int NT = 32;                   // 4096 / 128 tile-rows
constexpr int NBLK = NT * (NT + 1) / 2;  // 528 upper-triangle tiles
constexpr float SENT = -1e30f;           // sentinel (invalid sites / empty slots)

typedef _Float16 f16x8 __attribute__((ext_vector_type(8)));
typedef float f32x4 __attribute__((ext_vector_type(4)));

// raw barrier / fine-grained vmcnt (AITER-style pipeline; compiler must not
// see these as __syncthreads or it inserts a full vmcnt(0) drain)
#define BAR() asm volatile("s_barrier" ::: "memory")
#define WAITV8() asm volatile("s_waitcnt vmcnt(8)" ::: "memory")
#define WAITV0() asm volatile("s_waitcnt vmcnt(0)" ::: "memory")

// async 16B/lane global->LDS (wave-uniform LDS base + lane*16)
__device__ __forceinline__ void load_lds16(const _Float16* g, _Float16* l) {
  __builtin_amdgcn_global_load_lds(
      (const __attribute__((address_space(1))) void*)g,
      (__attribute__((address_space(3))) void*)l, 16, 0, 0);
}

// branchless sorted-desc top-10 insert
__device__ __forceinline__ void ins10(float (&t)[10], float v) {
#pragma unroll
  for (int k = 9; k > 0; k--) t[k] = fmaxf(t[k], fminf(v, t[k - 1]));
  t[0] = fmaxf(t[0], v);
}

// ws layout:
//   ws+0       f32 blk_sumv[528]; f32 blk_sump[528];
//              u32 blk_cntv[528]; u32 blk_cntp[528]; u32 blk_zero[528]
//   ws+10560   f32 top10g[528*10]       (per-block sorted top-10 lists)
//   ws+31744   f16 Xh[N*D]
constexpr int TOP10_OFF = 10560;
constexpr int XH_OFF = 31744;

// ---------------- K0: fp32 -> f16 convert ----------------
__global__ void prep_kernel(const float4* __restrict__ X4,
                            ushort4* __restrict__ Xh4) {
  int gid = blockIdx.x * 256 + threadIdx.x;  // grid exactly N*D/4 threads
  float4 v = X4[gid];
  ushort4 o;
  o.x = __half_as_ushort(__float2half_rn(v.x));
  o.y = __half_as_ushort(__float2half_rn(v.y));
  o.z = __half_as_ushort(__float2half_rn(v.z));
  o.w = __half_as_ushort(__float2half_rn(v.w));
  Xh4[gid] = o;
}

// ---------------- K1: upper-triangle tiled X*X^T + fused loss + in-block top-10 ----------------
// Double-buffered LDS (2 x 128x64 halves per operand), raw-barrier pipeline:
//   issue(it+1) -> s_waitcnt vmcnt(8) -> s_barrier -> compute(it)
// XOR swizzle: LDS pos p of row r holds global chunk p^(r&7).
__global__ __launch_bounds__(256, 2) void gemm_stats_kernel(
    const _Float16* __restrict__ Xh, const int* __restrict__ tgt,
    float* __restrict__ slots, float* __restrict__ top10g) {
  float* blk_sumv = slots;
  float* blk_sump = slots + NBLK;
  unsigned* blk_cntv = (unsigned*)(slots + 2 * NBLK);
  unsigned* blk_cntp = (unsigned*)(slots + 3 * NBLK);
  unsigned* blk_zero = (unsigned*)(slots + 4 * NBLK);

  __shared__ _Float16 As[2 * 128 * 64];  // 32 KB (double-buffered)
  __shared__ _Float16 Bs[2 * 128 * 64];  // 32 KB
  __shared__ float Lf[256 * 10];         // 10 KB (top-10 tree merge)
  __shared__ int tA[128], tB[128];
  __shared__ float redf[2][4];
  __shared__ unsigned redu[3][4];

  int tid = threadIdx.x;

  // decode upper-triangle tile (br <= bc)
  int id = blockIdx.x, br = 0;
  while (id >= (NT - br)) { id -= (NT - br); br++; }
  int bc = br + id;

  if (tid < 128) tA[tid] = tgt[br * 128 + tid];
  else           tB[tid - 128] = tgt[bc * 128 + (tid - 128)];

  int lane = tid & 63, wave = tid >> 6;
  int wm = (wave >> 1) << 6;
  int wn = (wave & 1) << 6;
  int lrow = lane & 15;
  int q4 = lane >> 4;  // quad 0..3
  int x7 = lrow & 7;   // swizzle key for ds_read side
  int quad4 = q4 * 4;

  // staging: issue i (0..3) covers chunks C=(i*4+wave)*64+lane;
  // row=C>>3, lds pos p=C&7 holds global chunk p^(row&7)
  int srow[4], scol[4], sdst[4];
#pragma unroll
  for (int i = 0; i < 4; i++) {
    int C = (i * 4 + wave) * 64 + lane;
    int row = C >> 3, p = C & 7;
    srow[i] = row;
    scol[i] = (p ^ (row & 7)) * 8;
    sdst[i] = (i * 4 + wave) * 512;
  }
  const _Float16* Arow = Xh + (size_t)(br * 128) * D;
  const _Float16* Brow = Xh + (size_t)(bc * 128) * D;

  auto issue = [&](int k0, int sel) {
#pragma unroll
    for (int i = 0; i < 4; i++) {
      load_lds16(Arow + srow[i] * D + k0 + scol[i], As + sel * 8192 + sdst[i]);
      load_lds16(Brow + srow[i] * D + k0 + scol[i], Bs + sel * 8192 + sdst[i]);
    }
  };

  f32x4 acc[4][4] = {};

  __syncthreads();  // tA/tB visible; drains all prior vm/lgkm
  issue(0, 0);      // cold prefetch of tile 0

#pragma unroll
  for (int it = 0; it < 8; ++it) {
    int sel = it & 1;
    if (it > 0) BAR();                // all waves done READING buffer sel^1
    if (it < 7) {
      issue((it + 1) * 64, sel ^ 1);  // prefetch next into the other buffer
      WAITV8();                       // drain only tile-it's 8 loads (~free)
    } else {
      WAITV0();
    }
    BAR();                            // all waves' tile-it deposits visible
#pragma unroll
    for (int ks = 0; ks < 64; ks += 32) {
      int c0 = ks >> 3;
      f16x8 af[4], bf[4];
#pragma unroll
      for (int mi = 0; mi < 4; mi++)
        af[mi] = *(const f16x8*)&As[sel * 8192 + (wm + mi * 16 + lrow) * 64 +
                                    ((c0 + q4) ^ x7) * 8];
#pragma unroll
      for (int ni = 0; ni < 4; ni++)
        bf[ni] = *(const f16x8*)&Bs[sel * 8192 + (wn + ni * 16 + lrow) * 64 +
                                    ((c0 + q4) ^ x7) * 8];
#pragma unroll
      for (int mi = 0; mi < 4; mi++)
#pragma unroll
        for (int ni = 0; ni < 4; ni++)
          acc[mi][ni] = __builtin_amdgcn_mfma_f32_16x16x32_f16(
              af[mi], bf[ni], acc[mi][ni], 0, 0, 0);
    }
  }

  // ---- fused epilogue: masks, hinge, stats, branchless per-thread top-10 ----
  int ti[4][4], tj[4];
#pragma unroll
  for (int ni = 0; ni < 4; ni++) tj[ni] = tB[wn + ni * 16 + lrow];
#pragma unroll
  for (int mi = 0; mi < 4; mi++)
#pragma unroll
    for (int r = 0; r < 4; r++) ti[mi][r] = tA[wm + mi * 16 + quad4 + r];

  float lsv = 0.f, lsp = 0.f;
  unsigned lcv = 0, lcp = 0, lz = 0;
  int ibase = br * 128 + wm + quad4;
  int jbase = bc * 128 + wn + lrow;

  float t10[10];
#pragma unroll
  for (int k = 0; k < 10; k++) t10[k] = SENT;

#pragma unroll
  for (int mi = 0; mi < 4; mi++)
#pragma unroll
    for (int ni = 0; ni < 4; ni++)
#pragma unroll
      for (int r = 0; r < 4; r++) {
        float s = acc[mi][ni][r];
        int i = ibase + mi * 16 + r;
        int j = jbase + ni * 16;
        bool valid = j > i;  // strict upper triangle; results doubled at the end
        bool pos = valid && (ti[mi][r] == tj[ni]);
        float t = pos ? -s : s;
        float loss = fmaxf(0.5f + t, 0.0f);
        if (valid) { lsv += s; lcv++; if (loss == 0.0f) lz++; }
        if (pos) { lsp += s; lcp++; }
        ins10(t10, valid ? loss : SENT);  // branchless, no atomics, no caps
      }

  // stats: wave shuffle reduce -> LDS -> per-block slots (plain stores)
#pragma unroll
  for (int o = 32; o > 0; o >>= 1) {
    lsv += __shfl_down(lsv, o);
    lsp += __shfl_down(lsp, o);
    lcv += __shfl_down(lcv, o);
    lcp += __shfl_down(lcp, o);
    lz  += __shfl_down(lz, o);
  }
  if (lane == 0) {
    redf[0][wave] = lsv; redf[1][wave] = lsp;
    redu[0][wave] = lcv; redu[1][wave] = lcp; redu[2][wave] = lz;
  }

  // top-10: per-thread lists -> LDS pairwise tree merge (8 levels)
#pragma unroll
  for (int k = 0; k < 10; k++) Lf[tid * 10 + k] = t10[k];
  for (int s2 = 128; s2 >= 1; s2 >>= 1) {
    __syncthreads();
    if (tid < s2) {
#pragma unroll
      for (int k = 0; k < 10; k++) ins10(t10, Lf[(tid + s2) * 10 + k]);
#pragma unroll
      for (int k = 0; k < 10; k++) Lf[tid * 10 + k] = t10[k];
    }
  }
  __syncthreads();

  if (tid == 0) {
    int b = blockIdx.x;
    blk_sumv[b] = redf[0][0] + redf[0][1] + redf[0][2] + redf[0][3];
    blk_sump[b] = redf[1][0] + redf[1][1] + redf[1][2] + redf[1][3];
    blk_cntv[b] = redu[0][0] + redu[0][1] + redu[0][2] + redu[0][3];
    blk_cntp[b] = redu[1][0] + redu[1][1] + redu[1][2] + redu[1][3];
    blk_zero[b] = redu[2][0] + redu[2][1] + redu[2][2] + redu[2][3];
#pragma unroll
    for (int k = 0; k < 10; k++) top10g[b * 10 + k] = t10[k];
  }
}

// ---------------- K2: stats + tiny top-10 merge (528*10 floats) + outputs ----------------
__global__ void finalize_kernel(const float* __restrict__ slots,
                                const float* __restrict__ top10g,
                                float* __restrict__ out) {
  const float* blk_sumv = slots;
  const float* blk_sump = slots + NBLK;
  const unsigned* blk_cntv = (const unsigned*)(slots + 2 * NBLK);
  const unsigned* blk_cntp = (const unsigned*)(slots + 3 * NBLK);
  const unsigned* blk_zero = (const unsigned*)(slots + 4 * NBLK);

  __shared__ float Lf[256 * 10];
  __shared__ float rf[2][4];
  __shared__ unsigned ru[3][4];

  int tid = threadIdx.x;
  int lane = tid & 63, wave = tid >> 6;

  // phase 1: stats
  float sv = 0.f, sp = 0.f;
  unsigned cv = 0, cp = 0, zz = 0;
  for (int b = tid; b < NBLK; b += 256) {
    sv += blk_sumv[b]; sp += blk_sump[b];
    cv += blk_cntv[b]; cp += blk_cntp[b]; zz += blk_zero[b];
  }
#pragma unroll
  for (int o = 32; o > 0; o >>= 1) {
    sv += __shfl_down(sv, o);
    sp += __shfl_down(sp, o);
    cv += __shfl_down(cv, o);
    cp += __shfl_down(cp, o);
    zz += __shfl_down(zz, o);
  }
  if (lane == 0) {
    rf[0][wave] = sv; rf[1][wave] = sp;
    ru[0][wave] = cv; ru[1][wave] = cp; ru[2][wave] = zz;
  }

  // phase 2: top-10 over 5280 floats, coalesced (21 iters/thread)
  float t[10];
#pragma unroll
  for (int k = 0; k < 10; k++) t[k] = SENT;
  for (int g = tid; g < NBLK * 10; g += 256) ins10(t, top10g[g]);
#pragma unroll
  for (int k = 0; k < 10; k++) Lf[tid * 10 + k] = t[k];

  // pairwise tree merge of 256 sorted lists
  for (int s = 128; s >= 1; s >>= 1) {
    __syncthreads();
    if (tid < s) {
#pragma unroll
      for (int k = 0; k < 10; k++) ins10(t, Lf[(tid + s) * 10 + k]);
#pragma unroll
      for (int k = 0; k < 10; k++) Lf[tid * 10 + k] = t[k];
    }
  }
  __syncthreads();

  if (tid == 0) {
    float topsum = 0.f;
#pragma unroll
    for (int k = 0; k < 10; k++) topsum += t[k];
    float tsv = rf[0][0] + rf[0][1] + rf[0][2] + rf[0][3];
    float tsp = rf[1][0] + rf[1][1] + rf[1][2] + rf[1][3];
    unsigned tcv = ru[0][0] + ru[0][1] + ru[0][2] + ru[0][3];
    unsigned tcp = ru[1][0] + ru[1][1] + ru[1][2] + ru[1][3];
    unsigned tzz = ru[2][0] + ru[2][1] + ru[2][2] + ru[2][3];
    // full-matrix multiset = upper-triangle doubled: top-20 mean == top-10 mean,
    // counts double in numerator and denominator (cancel in means)
    out[0] = topsum * 0.1f;
    out[1] = (float)(2u * tzz);
    out[2] = tsp / (float)tcp;
    out[3] = (tsv - tsp) / (float)(tcv - tcp);
  }
}

extern "C" void kernel_launch(void* const* d_in, const int* in_sizes, int n_in,
                              void* d_out, int out_size, void* d_ws, size_t ws_size,
                              hipStream_t stream) {
  const float* X = (const float*)d_in[0];
  const int* tgt = (const int*)d_in[1];
  float* out = (float*)d_out;
  char* ws = (char*)d_ws;

  float* slots = (float*)ws;
  float* top10g = (float*)(ws + TOP10_OFF);
  _Float16* Xh = (_Float16*)(ws + XH_OFF);

  prep_kernel<<<(N * D / 4) / 256, 256, 0, stream>>>((const float4*)X,
                                                     (ushort4*)Xh);
  gemm_stats_kernel<<<NBLK, 256, 0, stream>>>(Xh, tgt, slots, top10g);
  finalize_kernel<<<1, 256, 0, stream>>>(slots, top10g, out);
}